// Round 12
// baseline (151.469 us; speedup 1.0000x reference)
//
#include <hip/hip_runtime.h>
#include <hip/hip_bf16.h>

#define H_DIM 768
#define S_LEN 128
#define NT32 24  // 768 / 32 K-tiles

typedef __attribute__((ext_vector_type(8))) short short8;
typedef __attribute__((ext_vector_type(4))) float f32x4;

__device__ __forceinline__ void gload_lds16(const void* g, void* l) {
  __builtin_amdgcn_global_load_lds(
      (const __attribute__((address_space(1))) unsigned int*)g,
      (__attribute__((address_space(3))) unsigned int*)l, 16, 0, 0);
}

// ---------------- Kernel 1: per-token L2 normalize, fp32 -> bf16 (both tensors) ----------------
__global__ __launch_bounds__(256) void norm_bf16_kernel(
    const float* __restrict__ x1, const float* __restrict__ x2,
    unsigned short* __restrict__ xn1, unsigned short* __restrict__ xn2) {
  const int gid = blockIdx.x;
  const float* row;
  unsigned short* orow;
  if (gid < 8192) { row = x1 + (size_t)gid * H_DIM; orow = xn1 + (size_t)gid * H_DIM; }
  else            { row = x2 + (size_t)(gid - 8192) * H_DIM; orow = xn2 + (size_t)(gid - 8192) * H_DIM; }
  const int tid = threadIdx.x;
  float4 v = make_float4(0.f, 0.f, 0.f, 0.f);
  float ss = 0.f;
  if (tid < 192) {  // 192 * 4 = 768 floats
    v = reinterpret_cast<const float4*>(row)[tid];
    ss = v.x * v.x + v.y * v.y + v.z * v.z + v.w * v.w;
  }
#pragma unroll
  for (int o = 32; o > 0; o >>= 1) ss += __shfl_down(ss, o);
  __shared__ float ws[4];
  if ((tid & 63) == 0) ws[tid >> 6] = ss;
  __syncthreads();
  const float scale = 1.0f / sqrtf(ws[0] + ws[1] + ws[2] + ws[3]);
  if (tid < 192) {
    union { ushort4 u; __hip_bfloat16 h[4]; } o;
    o.h[0] = __float2bfloat16(v.x * scale);
    o.h[1] = __float2bfloat16(v.y * scale);
    o.h[2] = __float2bfloat16(v.z * scale);
    o.h[3] = __float2bfloat16(v.w * scale);
    reinterpret_cast<ushort4*>(orow)[tid] = o.u;
  }
}

// Stage one BK=32 K-tile into slot SLOT: A 128x32 (8 KB) at smem+SLOT*8192,
// B 256x32 (16 KB) at smem+24576+SLOT*16384. 3 gload_lds/thread. Linear LDS
// dest, inverse-swizzled GLOBAL source chunk (rule 21; involution (row>>1)&3).
#define STAGE32(SLOT, KT)                                                     \
  {                                                                           \
    const int k0e = (KT) * 32;                                                \
    gload_lds16(A0 + a_src + k0e, smem + (SLOT)*8192 + a_dst);                \
    gload_lds16(B0 + b_src0 + k0e, smem + 24576 + (SLOT)*16384 + b_dst0);     \
    gload_lds16(B0 + b_src1 + k0e, smem + 24576 + (SLOT)*16384 + b_dst1);     \
    __builtin_amdgcn_sched_barrier(0); /* keep DMA issue ahead of compute */  \
  }

// Compute one BK=32 K-tile from slot SLOT: 8 ds_read_b128 + 16 MFMA / wave.
#define COMPUTE32(SLOT)                                                       \
  {                                                                           \
    short8 av[4], bv[4];                                                      \
    _Pragma("unroll")                                                         \
    for (int i = 0; i < 4; ++i)                                               \
      av[i] = *reinterpret_cast<const short8*>(                               \
          smem + (SLOT)*8192 + aoff + i * 1024);                              \
    _Pragma("unroll")                                                         \
    for (int j = 0; j < 4; ++j)                                               \
      bv[j] = *reinterpret_cast<const short8*>(                               \
          smem + 24576 + (SLOT)*16384 + boff + j * 1024);                     \
    __builtin_amdgcn_s_setprio(1);                                            \
    _Pragma("unroll")                                                         \
    for (int i = 0; i < 4; ++i)                                               \
      _Pragma("unroll")                                                       \
      for (int j = 0; j < 4; ++j)                                             \
        acc[i][j] = __builtin_amdgcn_mfma_f32_16x16x32_bf16(                  \
            av[i], bv[j], acc[i][j], 0, 0, 0);                                \
    __builtin_amdgcn_s_setprio(0);                                            \
  }

// One pipeline step: stage tile T+2 (skipped at tail), compute tile T,
// counted vmcnt(3) -> tile T+1's DMAs (issued a FULL step ago, ~2 compute
// phases of cover) are retired while T+2's 3 stay in flight across the
// barrier. vmcnt is never 0 in steady state (T4).
#define TSTEP(SLOTC, SLOTS, T)                                                \
  {                                                                           \
    if ((T) + 2 < NT32) STAGE32(SLOTS, (T) + 2);                              \
    COMPUTE32(SLOTC);                                                         \
    if ((T) + 2 < NT32) { asm volatile("s_waitcnt vmcnt(3)" ::: "memory"); }  \
    else                { asm volatile("s_waitcnt vmcnt(0)" ::: "memory"); }  \
    __builtin_amdgcn_s_barrier();                                             \
  }

// ---------------- Kernel 2: one block = pair-batch (a, {b0,b1}), 128x256 tile ----------------
// R10 tile/epilogue + triple-buffered BK=32 K-pipeline (72 KB LDS -> still
// 2 blocks/CU). Masks in packed bitmask registers; rpart/cpart overlay the
// dead staging buffers after the K-loop.
__global__ __launch_bounds__(512, 2) void rwmd_kernel(
    const unsigned short* __restrict__ xn1, const unsigned short* __restrict__ xn2,
    const int* __restrict__ mask1, const int* __restrict__ mask2,
    float* __restrict__ out) {
  // layout: A slots [0,24K) = 3 x 8 KB; B slots [24K,72K) = 3 x 16 KB
  __shared__ __align__(16) unsigned char smem[73728];  // 72 KB
  float* const rpart = (float*)smem;                   // overlay: [4][128]
  float* const cpart = (float*)(smem + 2048);          // overlay: [2][256]

  const int a = blockIdx.x >> 5;   // 64 a's
  const int bp = blockIdx.x & 31;  // 32 b-pairs
  const int b0i = bp * 2;
  const int tid = threadIdx.x;
  const int lane = tid & 63;
  const int w = tid >> 6;
  const int wm = w >> 2, wn = w & 3;
  const int g = lane >> 4, rl = lane & 15;

  const unsigned short* A0 = xn1 + (size_t)a * (S_LEN * H_DIM);
  const unsigned short* B0 = xn2 + (size_t)b0i * (S_LEN * H_DIM);  // 256 rows

  // staging addresses (chunk = 16 B = 8 elems; 4 chunks per 32-elem row)
  const int ra = tid >> 2;                     // A row 0..127
  const int ca = (tid & 3) ^ ((ra >> 1) & 3);  // inverse-swizzled source chunk
  const size_t a_src = (size_t)ra * H_DIM + ca * 8;
  const int a_dst = tid * 16;                  // linear LDS bytes within slot
  const int sb0 = tid, sb1 = 512 + tid;        // B chunks 0..1023
  const int rb0 = sb0 >> 2, rb1 = sb1 >> 2;    // B rows 0..255
  const int cb0 = (sb0 & 3) ^ ((rb0 >> 1) & 3);
  const int cb1 = (sb1 & 3) ^ ((rb1 >> 1) & 3);
  const size_t b_src0 = (size_t)rb0 * H_DIM + cb0 * 8;
  const size_t b_src1 = (size_t)rb1 * H_DIM + cb1 * 8;
  const int b_dst0 = sb0 * 16, b_dst1 = sb1 * 16;

  // read addresses: row r holds k-chunk g at slot g^((r>>1)&3); for
  // r = base + rl (base mult of 16) this reduces to g^((rl>>1)&3).
  const int slot16 = g ^ ((rl >> 1) & 3);
  const int aoff = (wm * 64 + rl) * 64 + slot16 * 16;  // + i*1024
  const int boff = (wn * 64 + rl) * 64 + slot16 * 16;  // + j*1024

  f32x4 acc[4][4];
#pragma unroll
  for (int i = 0; i < 4; ++i)
#pragma unroll
    for (int j = 0; j < 4; ++j) acc[i][j] = (f32x4){0.f, 0.f, 0.f, 0.f};

  // prologue: tiles 0,1 staged; wait tile 0 (vmcnt(3): tile 1's 3 may fly)
  STAGE32(0, 0);
  STAGE32(1, 1);
  asm volatile("s_waitcnt vmcnt(3)" ::: "memory");
  __builtin_amdgcn_s_barrier();

#pragma unroll 1
  for (int t = 0; t < NT32; t += 3) {
    TSTEP(0, 2, t);      // compute t     (slot0), stage t+2 -> slot2
    TSTEP(1, 0, t + 1);  // compute t+1   (slot1), stage t+3 -> slot0
    TSTEP(2, 1, t + 2);  // compute t+2   (slot2), stage t+4 -> slot1
  }

  // ---- per-thread packed mask bits from global (L2-hot) ----
  __builtin_amdgcn_sched_barrier(0);
  unsigned mcol = 0, mrow = 0;
#pragma unroll
  for (int j = 0; j < 4; ++j)
    mcol |= (mask2[b0i * S_LEN + wn * 64 + j * 16 + rl] ? 1u : 0u) << j;
#pragma unroll
  for (int i = 0; i < 4; ++i)
#pragma unroll
    for (int r = 0; r < 4; ++r)
      mrow |= (mask1[a * S_LEN + wm * 64 + i * 16 + g * 4 + r] ? 1u : 0u) << (i * 4 + r);

  __syncthreads();  // staging LDS dead -> safe to overlay rpart/cpart

  // ---- in-register masked reductions ----
  // acc[i][j][r]: row = wm*64 + i*16 + g*4 + r, col = wn*64 + j*16 + rl
#pragma unroll
  for (int i = 0; i < 4; ++i) {
#pragma unroll
    for (int r = 0; r < 4; ++r) {
      float pm = -INFINITY;
#pragma unroll
      for (int j = 0; j < 4; ++j)
        pm = fmaxf(pm, ((mcol >> j) & 1) ? acc[i][j][r] : -INFINITY);
#pragma unroll
      for (int o = 1; o < 16; o <<= 1) pm = fmaxf(pm, __shfl_xor(pm, o));
      if (rl == 0) rpart[wn * S_LEN + wm * 64 + i * 16 + g * 4 + r] = pm;
    }
  }
#pragma unroll
  for (int j = 0; j < 4; ++j) {
    float cm = -INFINITY;
#pragma unroll
    for (int i = 0; i < 4; ++i)
#pragma unroll
      for (int r = 0; r < 4; ++r)
        cm = fmaxf(cm, ((mrow >> (i * 4 + r)) & 1) ? acc[i][j][r] : -INFINITY);
    cm = fmaxf(cm, __shfl_xor(cm, 16));
    cm = fmaxf(cm, __shfl_xor(cm, 32));
    if (g == 0) cpart[wm * 256 + wn * 64 + j * 16 + rl] = cm;
  }
  __syncthreads();

  // ---- final masked means: wave 0 -> pair b0, wave 1 -> pair b1 ----
  if (w < 2) {
    float v1 = 0.f, c1 = 0.f, v2 = 0.f, c2 = 0.f;
#pragma unroll
    for (int t = 0; t < 2; ++t) {
      const int r = lane + t * 64;
      if (mask1[a * S_LEN + r]) {
        v1 += fmaxf(rpart[(2 * w) * S_LEN + r], rpart[(2 * w + 1) * S_LEN + r]);
        c1 += 1.f;
      }
      const int c = w * 128 + lane + t * 64;
      if (mask2[b0i * S_LEN + c]) {
        v2 += fmaxf(cpart[c], cpart[256 + c]);
        c2 += 1.f;
      }
    }
#pragma unroll
    for (int o = 32; o > 0; o >>= 1) {
      v1 += __shfl_down(v1, o); c1 += __shfl_down(c1, o);
      v2 += __shfl_down(v2, o); c2 += __shfl_down(c2, o);
    }
    if (lane == 0) out[a * 64 + b0i + w] = 0.5f * (v1 / c1 + v2 / c2);
  }
}

extern "C" void kernel_launch(void* const* d_in, const int* in_sizes, int n_in,
                              void* d_out, int out_size, void* d_ws, size_t ws_size,
                              hipStream_t stream) {
  const float* x1 = (const float*)d_in[0];
  const int* mask1 = (const int*)d_in[1];
  const float* x2 = (const float*)d_in[2];
  const int* mask2 = (const int*)d_in[3];
  float* out = (float*)d_out;

  unsigned short* xn1 = (unsigned short*)d_ws;         // 64*128*768 bf16
  unsigned short* xn2 = xn1 + (size_t)64 * 128 * 768;  // 12.6 MB each

  norm_bf16_kernel<<<16384, 256, 0, stream>>>(x1, x2, xn1, xn2);
  rwmd_kernel<<<64 * 32, 512, 0, stream>>>(xn1, xn2, mask1, mask2, out);
}

// Round 13
// 105.431 us; speedup vs baseline: 1.4367x; 1.4367x over previous
//
#include <hip/hip_runtime.h>
#include <hip/hip_bf16.h>

#define H_DIM 768
#define S_LEN 128
#define NT 12  // 768 / 64 K-tiles

typedef __attribute__((ext_vector_type(8))) short short8;
typedef __attribute__((ext_vector_type(4))) float f32x4;

__device__ __forceinline__ void gload_lds16(const void* g, void* l) {
  __builtin_amdgcn_global_load_lds(
      (const __attribute__((address_space(1))) unsigned int*)g,
      (__attribute__((address_space(3))) unsigned int*)l, 16, 0, 0);
}

// ---------------- Kernel 0: per-sequence mask prefix-scan + pad zeroing ----------------
// 128 blocks (64 x1-seqs then 64 x2-seqs) x 128 threads. Computes compacted
// destination index per token (-1 if masked), real count, and zeroes the pad
// rows [n, ceil16(n)) of the compacted buffer.
__global__ __launch_bounds__(128) void prefix_kernel(
    const int* __restrict__ mask1, const int* __restrict__ mask2,
    int* __restrict__ dest, int* __restrict__ cnts,
    unsigned short* __restrict__ xc1, unsigned short* __restrict__ xc2) {
  const int sq = blockIdx.x;  // 0..127
  const int* mask = (sq < 64) ? (mask1 + sq * S_LEN) : (mask2 + (sq - 64) * S_LEN);
  unsigned short* xc = (sq < 64) ? (xc1 + (size_t)sq * S_LEN * H_DIM)
                                 : (xc2 + (size_t)(sq - 64) * S_LEN * H_DIM);
  const int tid = threadIdx.x;
  const int lane = tid & 63, wv = tid >> 6;
  const int m = mask[tid] ? 1 : 0;
  const unsigned long long bal = __ballot(m);
  const int pre = __popcll(bal & ((1ull << lane) - 1ull));
  __shared__ int wsum[2];
  if (lane == 0) wsum[wv] = __popcll(bal);
  __syncthreads();
  const int base = (wv == 1) ? wsum[0] : 0;
  const int n = wsum[0] + wsum[1];
  dest[sq * S_LEN + tid] = m ? (base + pre) : -1;
  if (tid == 0) cnts[sq] = n;
  // zero pad rows [n, np): excluded from max/mean by real-count compares,
  // but staged+MFMA'd (fragment granularity), so they must be zero.
  const int np = (n + 15) & ~15;
  const int nz = (np - n) * 96;  // short8 chunks
  for (int c = tid; c < nz; c += 128) {
    const int row = n + c / 96;
    *reinterpret_cast<short8*>(xc + (size_t)row * H_DIM + (c % 96) * 8) =
        (short8){0, 0, 0, 0, 0, 0, 0, 0};
  }
}

// ---------------- Kernel 1: per-token L2 normalize -> COMPACTED bf16 rows ----------------
__global__ __launch_bounds__(256) void normc_kernel(
    const float* __restrict__ x1, const float* __restrict__ x2,
    const int* __restrict__ dest,
    unsigned short* __restrict__ xc1, unsigned short* __restrict__ xc2) {
  const int gid = blockIdx.x;      // 0..16383
  const int sg = gid >> 7;         // combined sequence id 0..127
  const int tok = gid & 127;
  const int d = dest[sg * S_LEN + tok];
  if (d < 0) return;               // block-uniform: whole block exits
  const bool is1 = (gid < 8192);
  const float* row = is1 ? (x1 + (size_t)gid * H_DIM)
                         : (x2 + (size_t)(gid - 8192) * H_DIM);
  unsigned short* orow = is1 ? (xc1 + ((size_t)(sg)*S_LEN + d) * H_DIM)
                             : (xc2 + ((size_t)(sg - 64) * S_LEN + d) * H_DIM);
  const int tid = threadIdx.x;
  float4 v = make_float4(0.f, 0.f, 0.f, 0.f);
  float ss = 0.f;
  if (tid < 192) {
    v = reinterpret_cast<const float4*>(row)[tid];
    ss = v.x * v.x + v.y * v.y + v.z * v.z + v.w * v.w;
  }
#pragma unroll
  for (int o = 32; o > 0; o >>= 1) ss += __shfl_down(ss, o);
  __shared__ float ws[4];
  if ((tid & 63) == 0) ws[tid >> 6] = ss;
  __syncthreads();
  const float scale = 1.0f / sqrtf(ws[0] + ws[1] + ws[2] + ws[3]);
  if (tid < 192) {
    union { ushort4 u; __hip_bfloat16 h[4]; } o;
    o.h[0] = __float2bfloat16(v.x * scale);
    o.h[1] = __float2bfloat16(v.y * scale);
    o.h[2] = __float2bfloat16(v.z * scale);
    o.h[3] = __float2bfloat16(v.w * scale);
    reinterpret_cast<ushort4*>(orow)[tid] = o.u;
  }
}

// ---------------- Kernel 2: one block = one (a,b) pair, COMPACTED n1p x n2p tile ----------------
// 4 waves 2x2, fragment-interleaved: wave (wm,wn) owns fragments (2i+wm, 2j+wn)
// -> count guards are wave-uniform and acc indexing stays static (rule #20).
// Round-10 K-loop (stage -> drain -> compute, proven structure), single 32 KB
// buffer, 4 blocks/CU (16 waves) for cross-block drain hiding.
// Masking is index-based: col < n2 / row < n1 integer compares (no mask loads).
__global__ __launch_bounds__(256, 4) void rwmd_kernel(
    const unsigned short* __restrict__ xc1, const unsigned short* __restrict__ xc2,
    const int* __restrict__ cnts, float* __restrict__ out) {
  __shared__ __align__(16) unsigned short Al[S_LEN * 64];  // 16 KB [<=128][64]
  __shared__ __align__(16) unsigned short Bl[S_LEN * 64];  // 16 KB
  __shared__ float rpart[2][S_LEN];  // [wn][row] partial row-max
  __shared__ float cpart[2][S_LEN];  // [wm][col] partial col-max

  const int a = blockIdx.x >> 6;
  const int b = blockIdx.x & 63;
  const int n1 = cnts[a], n2 = cnts[64 + b];
  const int n1p = (n1 + 15) & ~15, n2p = (n2 + 15) & ~15;
  const int tid = threadIdx.x;
  const int lane = tid & 63;
  const int w = tid >> 6;
  const int wm = w >> 1, wn = w & 1;
  const int g = lane >> 4, rl = lane & 15;

  const unsigned short* A0 = xc1 + (size_t)a * (S_LEN * H_DIM);
  const unsigned short* B0 = xc2 + (size_t)b * (S_LEN * H_DIM);

  f32x4 acc[4][4];  // fragment (2i+wm, 2j+wn); inactive frags stay zero
#pragma unroll
  for (int i = 0; i < 4; ++i)
#pragma unroll
    for (int j = 0; j < 4; ++j) acc[i][j] = (f32x4){0.f, 0.f, 0.f, 0.f};

  for (int t = 0; t < NT; ++t) {
    __syncthreads();  // previous compute done before DMA overwrites LDS
    // stage rows < n1p / n2p only (exec-masked lanes; linear LDS dest,
    // inverse-swizzled global source chunk — rule 21)
#pragma unroll
    for (int q = 0; q < 4; ++q) {
      const int s = q * 256 + tid;           // chunk 0..1023
      const int row = s >> 3;
      const int cb = (s & 7) ^ (row & 7);
      const size_t src = (size_t)row * H_DIM + t * 64 + cb * 8;
      if (row < n1p) gload_lds16(A0 + src, Al + s * 8);
      if (row < n2p) gload_lds16(B0 + src, Bl + s * 8);
    }
    __syncthreads();  // drains vmcnt(0)
#pragma unroll
    for (int kf = 0; kf < 2; ++kf) {
      short8 av[4], bv[4];
      const int slot = (kf * 4 + g) ^ (rl & 7);  // frag row&7 == rl&7
#pragma unroll
      for (int i = 0; i < 4; ++i) {
        const int fr = (2 * i + wm) * 16;
        if (fr < n1p)
          av[i] = *reinterpret_cast<const short8*>(&Al[(fr + rl) * 64 + slot * 8]);
      }
#pragma unroll
      for (int j = 0; j < 4; ++j) {
        const int fc = (2 * j + wn) * 16;
        if (fc < n2p)
          bv[j] = *reinterpret_cast<const short8*>(&Bl[(fc + rl) * 64 + slot * 8]);
      }
      __builtin_amdgcn_s_setprio(1);
#pragma unroll
      for (int i = 0; i < 4; ++i)
#pragma unroll
        for (int j = 0; j < 4; ++j)
          if ((2 * i + wm) * 16 < n1p && (2 * j + wn) * 16 < n2p)
            acc[i][j] = __builtin_amdgcn_mfma_f32_16x16x32_bf16(
                av[i], bv[j], acc[i][j], 0, 0, 0);
      __builtin_amdgcn_s_setprio(0);
    }
  }

  // ---- in-register masked reductions (index-compare masking) ----
  // acc[i][j][r]: row = (2i+wm)*16 + g*4 + r, col = (2j+wn)*16 + rl
#pragma unroll
  for (int i = 0; i < 4; ++i) {
    const int rbase = (2 * i + wm) * 16;
#pragma unroll
    for (int r = 0; r < 4; ++r) {
      float pm = -INFINITY;
#pragma unroll
      for (int j = 0; j < 4; ++j) {
        const int col = (2 * j + wn) * 16 + rl;
        pm = fmaxf(pm, (col < n2) ? acc[i][j][r] : -INFINITY);
      }
#pragma unroll
      for (int o = 1; o < 16; o <<= 1) pm = fmaxf(pm, __shfl_xor(pm, o));
      if (rl == 0) rpart[wn][rbase + g * 4 + r] = pm;
    }
  }
#pragma unroll
  for (int j = 0; j < 4; ++j) {
    const int cbase = (2 * j + wn) * 16;
    float cm = -INFINITY;
#pragma unroll
    for (int i = 0; i < 4; ++i)
#pragma unroll
      for (int r = 0; r < 4; ++r) {
        const int row = (2 * i + wm) * 16 + g * 4 + r;
        cm = fmaxf(cm, (row < n1) ? acc[i][j][r] : -INFINITY);
      }
    cm = fmaxf(cm, __shfl_xor(cm, 16));
    cm = fmaxf(cm, __shfl_xor(cm, 32));
    if (g == 0) cpart[wm][cbase + rl] = cm;
  }
  __syncthreads();

  // ---- final masked means on wave 0 (denominators = real counts) ----
  if (w == 0) {
    float v1 = 0.f, v2 = 0.f;
#pragma unroll
    for (int t2 = 0; t2 < 2; ++t2) {
      const int r = lane + t2 * 64;
      if (r < n1) v1 += fmaxf(rpart[0][r], rpart[1][r]);
      if (r < n2) v2 += fmaxf(cpart[0][r], cpart[1][r]);
    }
#pragma unroll
    for (int o = 32; o > 0; o >>= 1) {
      v1 += __shfl_down(v1, o);
      v2 += __shfl_down(v2, o);
    }
    if (lane == 0) out[a * 64 + b] = 0.5f * (v1 / (float)n1 + v2 / (float)n2);
  }
}

extern "C" void kernel_launch(void* const* d_in, const int* in_sizes, int n_in,
                              void* d_out, int out_size, void* d_ws, size_t ws_size,
                              hipStream_t stream) {
  const float* x1 = (const float*)d_in[0];
  const int* mask1 = (const int*)d_in[1];
  const float* x2 = (const float*)d_in[2];
  const int* mask2 = (const int*)d_in[3];
  float* out = (float*)d_out;

  unsigned short* xc1 = (unsigned short*)d_ws;               // 12.58 MB compacted A
  unsigned short* xc2 = xc1 + (size_t)64 * S_LEN * H_DIM;    // 12.58 MB compacted B
  int* dest = (int*)(xc2 + (size_t)64 * S_LEN * H_DIM);      // 128*128 ints
  int* cnts = dest + 128 * S_LEN;                            // 128 ints

  prefix_kernel<<<128, 128, 0, stream>>>(mask1, mask2, dest, cnts, xc1, xc2);
  normc_kernel<<<16384, 256, 0, stream>>>(x1, x2, dest, xc1, xc2);
  rwmd_kernel<<<64 * 64, 256, 0, stream>>>(xc1, xc2, cnts, out);
}